// Round 1
// baseline (223.084 us; speedup 1.0000x reference)
//
#include <hip/hip_runtime.h>

typedef unsigned int u32;
typedef int  v4i  __attribute__((ext_vector_type(4)));
typedef u32  u32x4 __attribute__((ext_vector_type(4)));

#define WSCALE 512.0f
#define INV16S (1.0f / 8192.0f)   // 1/(16*WSCALE)

// ---- weight prep: fp32 OIHW (64,64,3,3) -> int8 [o][tap(r*3+s)][c] = [64][9][64] ----
__global__ void wprep_kernel(const float* __restrict__ w, signed char* __restrict__ wq) {
  int i = blockIdx.x * 256 + threadIdx.x;
  if (i >= 64 * 9 * 64) return;
  int o = i / 576;
  int rem = i - o * 576;
  int tap = rem >> 6;          // 0..8
  int c = rem & 63;
  int r = tap / 3, s = tap - 3 * r;
  float v = w[((o * 64 + c) * 3 + r) * 3 + s];
  float q = rintf(v * WSCALE);
  q = fminf(fmaxf(q, -127.0f), 127.0f);
  wq[i] = (signed char)(int)q;
}

// ---- main fused kernel: bit-plane conv via i8 MFMA + per-bit quant + recombine ----
__launch_bounds__(256, 2)
__global__ void conv_kernel(const float* __restrict__ x,
                            const signed char* __restrict__ wq,
                            const float* __restrict__ bias,
                            float* __restrict__ out) {
  __shared__ __align__(16) signed char  swq[64 * 592];     // weights, row-padded 576->592B (2-way banks)
  __shared__ __align__(16) unsigned char spatch[6 * 18 * 80]; // input patch, px stride 64->80B
  __shared__ float sbias[64];

  const int tid = threadIdx.x;
  const int bid = blockIdx.x;
  const int b = bid / 196;
  const int rem = bid - b * 196;
  const int ht = rem / 7;
  const int wt = rem - ht * 7;
  const int h0 = ht * 4, w0 = wt * 16;

  // stage int8 weights: 36864 B = 2304 x 16B chunks, re-padded to 592B rows
  #pragma unroll
  for (int i = 0; i < 9; ++i) {
    int ci = tid + i * 256;           // 0..2303
    int o = ci / 36, k = ci - o * 36; // 36 chunks of 16B per 576B row
    *(u32x4*)&swq[o * 592 + k * 16] = ((const u32x4*)wq)[ci];
  }
  if (tid < 64) sbias[tid] = bias[tid];

  // stage input patch (6 rows x 18 cols x 64 ch) as clipped int8, zero-padded OOB
  for (int e = tid; e < 6 * 18 * 64; e += 256) {
    int c = e / 108;
    int pix = e - c * 108;
    int ph = pix / 18, pw = pix - ph * 18;
    int gh = h0 + ph, gw = w0 + pw;
    float v = 0.0f;
    if (gh < 112 && gw < 112)
      v = x[((b * 64 + c) * 112 + gh) * 112 + gw];
    v = fminf(fmaxf(v, -128.0f), 127.0f);
    spatch[(ph * 18 + pw) * 80 + c] = (unsigned char)(int)v;   // trunc-toward-zero, 2's complement
  }
  __syncthreads();

  const int lane = tid & 63, wid = tid >> 6;
  const int p = lane & 15, kg = lane >> 4;

  v4i acc[8][4];
  #pragma unroll
  for (int k = 0; k < 8; ++k)
    #pragma unroll
    for (int m = 0; m < 4; ++m)
      acc[k][m] = (v4i){0, 0, 0, 0};

  #pragma unroll
  for (int tap = 0; tap < 9; ++tap) {
    const int r = tap / 3, s = tap - 3 * (tap / 3);
    // B bytes: 16 channels of the patch at (row wid+r, col p+s)
    u32x4 wb = *(const u32x4*)&spatch[((wid + r) * 18 + (p + s)) * 80 + kg * 16];
    // A frags: weights for this tap, 4 M-fragments (64 out channels)
    v4i a0 = *(const v4i*)&swq[(p     ) * 592 + tap * 64 + kg * 16];
    v4i a1 = *(const v4i*)&swq[(p + 16) * 592 + tap * 64 + kg * 16];
    v4i a2 = *(const v4i*)&swq[(p + 32) * 592 + tap * 64 + kg * 16];
    v4i a3 = *(const v4i*)&swq[(p + 48) * 592 + tap * 64 + kg * 16];
    #pragma unroll
    for (int bit = 0; bit < 8; ++bit) {
      v4i bb;
      bb[0] = (int)((wb[0] >> bit) & 0x01010101u);
      bb[1] = (int)((wb[1] >> bit) & 0x01010101u);
      bb[2] = (int)((wb[2] >> bit) & 0x01010101u);
      bb[3] = (int)((wb[3] >> bit) & 0x01010101u);
      acc[bit][0] = __builtin_amdgcn_mfma_i32_16x16x64_i8(a0, bb, acc[bit][0], 0, 0, 0);
      acc[bit][1] = __builtin_amdgcn_mfma_i32_16x16x64_i8(a1, bb, acc[bit][1], 0, 0, 0);
      acc[bit][2] = __builtin_amdgcn_mfma_i32_16x16x64_i8(a2, bb, acc[bit][2], 0, 0, 0);
      acc[bit][3] = __builtin_amdgcn_mfma_i32_16x16x64_i8(a3, bb, acc[bit][3], 0, 0, 0);
    }
  }

  // epilogue: per-bit quantize, two's-complement recombine, +bias, store
  const int orow = h0 + wid, ocol = w0 + p;
  const bool valid = (orow < 110) && (ocol < 110);
  #pragma unroll
  for (int m = 0; m < 4; ++m) {
    #pragma unroll
    for (int j = 0; j < 4; ++j) {
      const int o = m * 16 + kg * 4 + j;
      float s = sbias[o];
      #pragma unroll
      for (int bit = 0; bit < 8; ++bit) {
        const float pw16 = (bit < 7) ? (float)(16 << bit) : -2048.0f;
        float q = rintf((float)acc[bit][m][j] * INV16S);
        q = fminf(fmaxf(q, -128.0f), 127.0f);
        s = fmaf(pw16, q, s);
      }
      if (valid)
        out[((b * 64 + o) * 110 + orow) * 110 + ocol] = s;
    }
  }
}

extern "C" void kernel_launch(void* const* d_in, const int* in_sizes, int n_in,
                              void* d_out, int out_size, void* d_ws, size_t ws_size,
                              hipStream_t stream) {
  const float* x    = (const float*)d_in[0];
  const float* w    = (const float*)d_in[1];
  const float* bias = (const float*)d_in[2];
  float* out = (float*)d_out;
  signed char* wq = (signed char*)d_ws;

  hipLaunchKernelGGL(wprep_kernel, dim3(144), dim3(256), 0, stream, w, wq);
  // grid: 16 batches x 28 h-tiles(4 rows) x 7 w-tiles(16 cols) = 3136 WGs
  hipLaunchKernelGGL(conv_kernel, dim3(16 * 28 * 7), dim3(256), 0, stream, x, wq, bias, out);
}